// Round 1
// baseline (1688.284 us; speedup 1.0000x reference)
//
#include <hip/hip_runtime.h>
#include <hip/hip_bf16.h>

#define NEX 4096
#define M   256
#define D1  64
#define NM  (NEX*M)

// ---------------- small prep kernels ----------------

__global__ void k_symA(const float* __restrict__ A, float* __restrict__ symA) {
    int idx = blockIdx.x * 256 + threadIdx.x;   // 4096 entries
    int i = idx >> 6, j = idx & 63;
    float s = 0.f;
    #pragma unroll
    for (int r = 0; r < 10; r++) s += A[r*64+i] * A[r*64+j];
    symA[idx] = s;
}

// dst[c*rows + r] = src[r*cols + c]
__global__ void k_transpose(const float* __restrict__ src, float* __restrict__ dst,
                            int rows, int cols) {
    int idx = blockIdx.x * 256 + threadIdx.x;
    int total = rows * cols;
    if (idx < total) {
        int c = idx / rows, r = idx % rows;
        dst[idx] = src[r*cols + c];
    }
}

__global__ void k_misc(const float* __restrict__ W0, const float* __restrict__ A,
                       float* __restrict__ ksq, float* __restrict__ trace) {
    int t = threadIdx.x;
    float s = 0.f;
    for (int dd = 0; dd < 63; dd++) { float v = W0[t*64+dd]; s += v*v; }
    ksq[t] = s;
    float p = 0.f;
    for (int idx = t; idx < 630; idx += 256) {
        int r = idx / 63, i = idx % 63;
        float v = A[r*64+i]; p += v*v;
    }
    for (int off = 32; off; off >>= 1) p += __shfl_down(p, off, 64);
    __shared__ float red[4];
    if ((t & 63) == 0) red[t >> 6] = p;
    __syncthreads();
    if (t == 0) trace[0] = red[0]+red[1]+red[2]+red[3];
}

// ---------------- opening: 16 examples per block ----------------

__global__ void k_opening(const float* __restrict__ x, const float* __restrict__ W0T,
                          const float* __restrict__ b0,
                          float* __restrict__ tanhopen, float* __restrict__ u0) {
    __shared__ float xs[16*64];
    int n0 = blockIdx.x * 16, t = threadIdx.x;
    #pragma unroll
    for (int i = 0; i < 4; i++) { int f = t + i*256; xs[f] = x[n0*64 + f]; }
    __syncthreads();
    float acc[16];
    float b = b0[t];
    #pragma unroll
    for (int j = 0; j < 16; j++) acc[j] = b;
    for (int c = 0; c < 64; c++) {
        float w = W0T[c*256 + t];
        #pragma unroll
        for (int j = 0; j < 16; j++) acc[j] += w * xs[j*64 + c];
    }
    for (int j = 0; j < 16; j++) {
        float p = acc[j];
        int o = (n0+j)*256 + t;
        tanhopen[o] = tanhf(p);
        float a = fabsf(p);
        u0[o] = a + log1pf(expf(-2.f*a));
    }
}

// pre0 = u0 @ Wd0^T + bd0 ; outputs tanh(pre0) and u1 = u0 + 0.5*antideriv(pre0)
__global__ void k_pre0(const float* __restrict__ u0, const float* __restrict__ Wd0T,
                       const float* __restrict__ bd0,
                       float* __restrict__ tp0, float* __restrict__ u1) {
    __shared__ float us[16*256];
    int n0 = blockIdx.x * 16, t = threadIdx.x;
    #pragma unroll
    for (int i = 0; i < 16; i++) us[t + i*256] = u0[n0*256 + t + i*256];
    __syncthreads();
    float acc[16];
    float b = bd0[t];
    #pragma unroll
    for (int j = 0; j < 16; j++) acc[j] = b;
    for (int k = 0; k < 256; k++) {
        float w = Wd0T[k*256 + t];
        #pragma unroll
        for (int j = 0; j < 16; j++) acc[j] += w * us[j*256 + k];
    }
    for (int j = 0; j < 16; j++) {
        float p = acc[j];
        int o = (n0+j)*256 + t;
        tp0[o] = tanhf(p);
        float a = fabsf(p);
        u1[o] = us[j*256 + t] + 0.5f*(a + log1pf(expf(-2.f*a)));
    }
}

// pre1 = u1 @ Wd1^T + bd1 ; output tanh(pre1)
__global__ void k_pre1(const float* __restrict__ u1, const float* __restrict__ Wd1T,
                       const float* __restrict__ bd1, float* __restrict__ tp1) {
    __shared__ float us[16*256];
    int n0 = blockIdx.x * 16, t = threadIdx.x;
    #pragma unroll
    for (int i = 0; i < 16; i++) us[t + i*256] = u1[n0*256 + t + i*256];
    __syncthreads();
    float acc[16];
    float b = bd1[t];
    #pragma unroll
    for (int j = 0; j < 16; j++) acc[j] = b;
    for (int k = 0; k < 256; k++) {
        float w = Wd1T[k*256 + t];
        #pragma unroll
        for (int j = 0; j < 16; j++) acc[j] += w * us[j*256 + k];
    }
    for (int j = 0; j < 16; j++) {
        int o = (n0+j)*256 + t;
        tp1[o] = tanhf(acc[j]);
    }
}

// z2T[n,k] = wv[k] + 0.5 * sum_m tp1[n,m]*wv[m]*Wd1[m,k]
__global__ void k_z2(const float* __restrict__ tp1, const float* __restrict__ wv,
                     const float* __restrict__ Wd1, float* __restrict__ z2T) {
    __shared__ float coef[16*256];
    int n0 = blockIdx.x * 16, t = threadIdx.x;
    #pragma unroll
    for (int i = 0; i < 16; i++) {
        int f = t + i*256;
        coef[f] = tp1[n0*256 + f] * wv[f & 255];
    }
    __syncthreads();
    float acc[16];
    #pragma unroll
    for (int j = 0; j < 16; j++) acc[j] = 0.f;
    for (int m = 0; m < 256; m++) {
        float w = Wd1[m*256 + t];
        #pragma unroll
        for (int j = 0; j < 16; j++) acc[j] += w * coef[j*256 + m];
    }
    float wvt = wv[t];
    for (int j = 0; j < 16; j++) z2T[(n0+j)*256 + t] = wvt + 0.5f*acc[j];
}

// z1T[n,k] = z2T[n,k] + 0.5 * sum_m tp0[n,m]*z2T[n,m]*Wd0[m,k]
__global__ void k_z1(const float* __restrict__ tp0, const float* __restrict__ z2T,
                     const float* __restrict__ Wd0, float* __restrict__ z1T) {
    __shared__ float coef[16*256];
    int n0 = blockIdx.x * 16, t = threadIdx.x;
    #pragma unroll
    for (int i = 0; i < 16; i++) {
        int f = t + i*256;
        coef[f] = tp0[n0*256 + f] * z2T[n0*256 + f];
    }
    __syncthreads();
    float acc[16];
    #pragma unroll
    for (int j = 0; j < 16; j++) acc[j] = 0.f;
    for (int m = 0; m < 256; m++) {
        float w = Wd0[m*256 + t];
        #pragma unroll
        for (int j = 0; j < 16; j++) acc[j] += w * coef[j*256 + m];
    }
    for (int j = 0; j < 16; j++) {
        int o = (n0+j)*256 + t;
        z1T[o] = z2T[o] + 0.5f*acc[j];
    }
}

// grad[n,c] = sum_m tanhopen[n,m]*z1T[n,m]*W0[m,c] + sum_j symA[c,j]*x[n,j] + cw[c]
__global__ void k_grad(const float* __restrict__ tanhopen, const float* __restrict__ z1T,
                       const float* __restrict__ W0, const float* __restrict__ symA,
                       const float* __restrict__ x, const float* __restrict__ cw,
                       float* __restrict__ out) {
    __shared__ float coef[16*256];
    __shared__ float sa[64*64];
    __shared__ float xs[16*64];
    __shared__ float cws[64];
    int n0 = blockIdx.x * 16, t = threadIdx.x;
    #pragma unroll
    for (int i = 0; i < 16; i++) {
        int f = t + i*256;
        coef[f] = tanhopen[n0*256 + f] * z1T[n0*256 + f];
        sa[f] = symA[f];
    }
    #pragma unroll
    for (int i = 0; i < 4; i++) { int f = t + i*256; xs[f] = x[n0*64 + f]; }
    if (t < 64) cws[t] = cw[t];
    __syncthreads();
    int c = t & 63, jj = t >> 6;
    float acc[4] = {0.f, 0.f, 0.f, 0.f};
    for (int m = 0; m < 256; m++) {
        float w0v = W0[m*64 + c];
        #pragma unroll
        for (int jb = 0; jb < 4; jb++) acc[jb] += coef[(jj + jb*4)*256 + m] * w0v;
    }
    for (int jb = 0; jb < 4; jb++) {
        int j = jj + jb*4;
        float g2 = 0.f;
        for (int jd = 0; jd < 64; jd++) g2 += sa[jd*64 + c] * xs[j*64 + jd];  // symA symmetric
        out[(n0+j)*64 + c] = acc[jb] + g2 + cws[c];
    }
}

// ---------------- heavy per-example Jacobian kernel ----------------
// one block per example; thread t owns KJ row m=t
__global__ __launch_bounds__(256) void k_heavy(
        const float* __restrict__ tanhopen, const float* __restrict__ tp0,
        const float* __restrict__ tp1, const float* __restrict__ z2T,
        const float* __restrict__ z1T, const float* __restrict__ wv,
        const float* __restrict__ W0, const float* __restrict__ Wd0T,
        const float* __restrict__ Wd1T, const float* __restrict__ ksq,
        const float* __restrict__ trace, float* __restrict__ outTrH) {
    __shared__ __align__(16) float Jac[256*64];
    __shared__ float s[256], w1[256], w2[256], tp0s[256];
    __shared__ float red[4];
    int n = blockIdx.x, t = threadIdx.x;
    float sv   = tanhopen[n*256 + t];
    float tp0v = tp0[n*256 + t];
    float tp1v = tp1[n*256 + t];
    float z2v  = z2T[n*256 + t];
    s[t]   = sv;
    tp0s[t] = tp0v;
    w1[t]  = (1.f - tp0v*tp0v) * z2v;
    w2[t]  = (1.f - tp1v*tp1v) * wv[t];
    float tot = (1.f - sv*sv) * z1T[n*256 + t] * ksq[t];   // trH0 partial
    __syncthreads();
    // Jac[k][dd] = W0[k][dd] * s[k], column 63 zeroed (Kopen = W0[:, :63])
    #pragma unroll 4
    for (int i = 0; i < 64; i++) {
        int idx = t + i*256;
        int k = idx >> 6, dd = idx & 63;
        Jac[idx] = (dd == 63) ? 0.f : W0[idx] * s[k];
    }
    __syncthreads();

    float4 acc[16];
    // ---- layer 0: KJ = Wd0 @ Jac ----
    #pragma unroll
    for (int q = 0; q < 16; q++) acc[q] = make_float4(0.f,0.f,0.f,0.f);
    for (int k = 0; k < 256; k++) {
        float wk = Wd0T[k*256 + t];
        const float4* jr = (const float4*)&Jac[k*64];
        #pragma unroll
        for (int q = 0; q < 16; q++) {
            float4 jv = jr[q];
            acc[q].x += wk*jv.x; acc[q].y += wk*jv.y;
            acc[q].z += wk*jv.z; acc[q].w += wk*jv.w;
        }
    }
    float ss = 0.f;
    #pragma unroll
    for (int q = 0; q < 16; q++)
        ss += acc[q].x*acc[q].x + acc[q].y*acc[q].y + acc[q].z*acc[q].z + acc[q].w*acc[q].w;
    tot += 0.5f * w1[t] * ss;
    __syncthreads();
    // ---- Jac row t += 0.5*tanh(pre0)[t] * KJ row t ----
    {
        float f = 0.5f * tp0s[t];
        float4* jr = (float4*)&Jac[t*64];
        #pragma unroll
        for (int q = 0; q < 16; q++) {
            float4 jv = jr[q];
            jv.x += f*acc[q].x; jv.y += f*acc[q].y;
            jv.z += f*acc[q].z; jv.w += f*acc[q].w;
            jr[q] = jv;
        }
    }
    __syncthreads();
    // ---- layer 1: KJ2 = Wd1 @ Jac ----
    #pragma unroll
    for (int q = 0; q < 16; q++) acc[q] = make_float4(0.f,0.f,0.f,0.f);
    for (int k = 0; k < 256; k++) {
        float wk = Wd1T[k*256 + t];
        const float4* jr = (const float4*)&Jac[k*64];
        #pragma unroll
        for (int q = 0; q < 16; q++) {
            float4 jv = jr[q];
            acc[q].x += wk*jv.x; acc[q].y += wk*jv.y;
            acc[q].z += wk*jv.z; acc[q].w += wk*jv.w;
        }
    }
    ss = 0.f;
    #pragma unroll
    for (int q = 0; q < 16; q++)
        ss += acc[q].x*acc[q].x + acc[q].y*acc[q].y + acc[q].z*acc[q].z + acc[q].w*acc[q].w;
    tot += 0.5f * w2[t] * ss;

    // reduce 256 -> 1
    for (int off = 32; off; off >>= 1) tot += __shfl_down(tot, off, 64);
    if ((t & 63) == 0) red[t >> 6] = tot;
    __syncthreads();
    if (t == 0) outTrH[n] = red[0]+red[1]+red[2]+red[3] + trace[0];
}

// ---------------- launcher ----------------

extern "C" void kernel_launch(void* const* d_in, const int* in_sizes, int n_in,
                              void* d_out, int out_size, void* d_ws, size_t ws_size,
                              hipStream_t stream) {
    const float* x   = (const float*)d_in[0];   // 4096*64
    const float* W0  = (const float*)d_in[1];   // 256*64
    const float* b0  = (const float*)d_in[2];   // 256
    const float* Wd  = (const float*)d_in[3];   // 2*256*256
    const float* bd  = (const float*)d_in[4];   // 2*256
    const float* wv  = (const float*)d_in[5];   // 256
    const float* A   = (const float*)d_in[6];   // 10*64
    const float* cw  = (const float*)d_in[7];   // 64
    float* out = (float*)d_out;
    float* ws  = (float*)d_ws;

    float* tanhopen = ws;               // NM
    float* u0   = tanhopen + NM;        // NM
    float* u1   = u0 + NM;              // NM
    float* tp0  = u1 + NM;              // NM
    float* tp1  = tp0 + NM;             // NM
    float* z2T  = tp1 + NM;             // NM
    float* z1T  = z2T + NM;             // NM
    float* Wd0T = z1T + NM;             // 65536
    float* Wd1T = Wd0T + 65536;         // 65536
    float* W0T  = Wd1T + 65536;         // 16384
    float* symA = W0T + 16384;          // 4096
    float* ksq  = symA + 4096;          // 256
    float* trace= ksq + 256;            // 1

    const float* Wd0 = Wd;
    const float* Wd1 = Wd + 65536;

    k_symA<<<16, 256, 0, stream>>>(A, symA);
    k_transpose<<<256, 256, 0, stream>>>(Wd0, Wd0T, 256, 256);
    k_transpose<<<256, 256, 0, stream>>>(Wd1, Wd1T, 256, 256);
    k_transpose<<<64, 256, 0, stream>>>(W0, W0T, 256, 64);
    k_misc<<<1, 256, 0, stream>>>(W0, A, ksq, trace);

    k_opening<<<NEX/16, 256, 0, stream>>>(x, W0T, b0, tanhopen, u0);
    k_pre0<<<NEX/16, 256, 0, stream>>>(u0, Wd0T, bd, tp0, u1);
    k_pre1<<<NEX/16, 256, 0, stream>>>(u1, Wd1T, bd + 256, tp1);
    k_z2<<<NEX/16, 256, 0, stream>>>(tp1, wv, Wd1, z2T);
    k_z1<<<NEX/16, 256, 0, stream>>>(tp0, z2T, Wd0, z1T);
    k_grad<<<NEX/16, 256, 0, stream>>>(tanhopen, z1T, W0, symA, x, cw, out);
    k_heavy<<<NEX, 256, 0, stream>>>(tanhopen, tp0, tp1, z2T, z1T, wv,
                                     W0, Wd0T, Wd1T, ksq, trace, out + NEX*64);
}

// Round 2
// 476.475 us; speedup vs baseline: 3.5433x; 3.5433x over previous
//
#include <hip/hip_runtime.h>
#include <hip/hip_bf16.h>

#define NEX 4096
#define M   256
#define NM  (NEX*M)
#define JSTR 264   // padded JacT row stride in bf16 elements (16B-aligned, bank-skewed)

typedef __attribute__((ext_vector_type(8))) short short8;
typedef __attribute__((ext_vector_type(4))) float floatx4;

__device__ inline unsigned short f2bfu(float x) {
    __hip_bfloat16 h = __float2bfloat16(x);
    union { __hip_bfloat16 b; unsigned short u; } cv; cv.b = h;
    return cv.u;
}
__device__ inline float bfu2f(unsigned short u) {
    union { unsigned short u; __hip_bfloat16 b; } cv; cv.u = u;
    return __bfloat162float(cv.b);
}

// ---------------- small prep kernels ----------------

__global__ void k_symA(const float* __restrict__ A, float* __restrict__ symA) {
    int idx = blockIdx.x * 256 + threadIdx.x;   // 4096 entries
    int i = idx >> 6, j = idx & 63;
    float s = 0.f;
    #pragma unroll
    for (int r = 0; r < 10; r++) s += A[r*64+i] * A[r*64+j];
    symA[idx] = s;
}

__global__ void k_transpose(const float* __restrict__ src, float* __restrict__ dst,
                            int rows, int cols) {
    int idx = blockIdx.x * 256 + threadIdx.x;
    int total = rows * cols;
    if (idx < total) {
        int c = idx / rows, r = idx % rows;
        dst[idx] = src[r*cols + c];
    }
}

// split Wd (131072 floats) into hi/lo bf16
__global__ void k_split(const float* __restrict__ Wd, unsigned short* __restrict__ hi,
                        unsigned short* __restrict__ lo) {
    int idx = blockIdx.x * 256 + threadIdx.x;
    float x = Wd[idx];
    unsigned short h = f2bfu(x);
    hi[idx] = h;
    lo[idx] = f2bfu(x - bfu2f(h));
}

__global__ void k_misc(const float* __restrict__ W0, const float* __restrict__ A,
                       float* __restrict__ ksq, float* __restrict__ trace) {
    int t = threadIdx.x;
    float s = 0.f;
    for (int dd = 0; dd < 63; dd++) { float v = W0[t*64+dd]; s += v*v; }
    ksq[t] = s;
    float p = 0.f;
    for (int idx = t; idx < 630; idx += 256) {
        int r = idx / 63, i = idx % 63;
        float v = A[r*64+i]; p += v*v;
    }
    for (int off = 32; off; off >>= 1) p += __shfl_down(p, off, 64);
    __shared__ float red[4];
    if ((t & 63) == 0) red[t >> 6] = p;
    __syncthreads();
    if (t == 0) trace[0] = red[0]+red[1]+red[2]+red[3];
}

// ---------------- feature/adjoint chain (16 examples per block) ----------------

__global__ void k_opening(const float* __restrict__ x, const float* __restrict__ W0T,
                          const float* __restrict__ b0,
                          float* __restrict__ tanhopen, float* __restrict__ u0) {
    __shared__ float xs[16*64];
    int n0 = blockIdx.x * 16, t = threadIdx.x;
    #pragma unroll
    for (int i = 0; i < 4; i++) { int f = t + i*256; xs[f] = x[n0*64 + f]; }
    __syncthreads();
    float acc[16];
    float b = b0[t];
    #pragma unroll
    for (int j = 0; j < 16; j++) acc[j] = b;
    for (int c = 0; c < 64; c++) {
        float w = W0T[c*256 + t];
        #pragma unroll
        for (int j = 0; j < 16; j++) acc[j] += w * xs[j*64 + c];
    }
    for (int j = 0; j < 16; j++) {
        float p = acc[j];
        int o = (n0+j)*256 + t;
        tanhopen[o] = tanhf(p);
        float a = fabsf(p);
        u0[o] = a + log1pf(expf(-2.f*a));
    }
}

__global__ void k_pre0(const float* __restrict__ u0, const float* __restrict__ Wd0T,
                       const float* __restrict__ bd0,
                       float* __restrict__ tp0, float* __restrict__ u1) {
    __shared__ float us[16*256];
    int n0 = blockIdx.x * 16, t = threadIdx.x;
    #pragma unroll
    for (int i = 0; i < 16; i++) us[t + i*256] = u0[n0*256 + t + i*256];
    __syncthreads();
    float acc[16];
    float b = bd0[t];
    #pragma unroll
    for (int j = 0; j < 16; j++) acc[j] = b;
    for (int k = 0; k < 256; k++) {
        float w = Wd0T[k*256 + t];
        #pragma unroll
        for (int j = 0; j < 16; j++) acc[j] += w * us[j*256 + k];
    }
    for (int j = 0; j < 16; j++) {
        float p = acc[j];
        int o = (n0+j)*256 + t;
        tp0[o] = tanhf(p);
        float a = fabsf(p);
        u1[o] = us[j*256 + t] + 0.5f*(a + log1pf(expf(-2.f*a)));
    }
}

__global__ void k_pre1(const float* __restrict__ u1, const float* __restrict__ Wd1T,
                       const float* __restrict__ bd1, float* __restrict__ tp1) {
    __shared__ float us[16*256];
    int n0 = blockIdx.x * 16, t = threadIdx.x;
    #pragma unroll
    for (int i = 0; i < 16; i++) us[t + i*256] = u1[n0*256 + t + i*256];
    __syncthreads();
    float acc[16];
    float b = bd1[t];
    #pragma unroll
    for (int j = 0; j < 16; j++) acc[j] = b;
    for (int k = 0; k < 256; k++) {
        float w = Wd1T[k*256 + t];
        #pragma unroll
        for (int j = 0; j < 16; j++) acc[j] += w * us[j*256 + k];
    }
    for (int j = 0; j < 16; j++) {
        int o = (n0+j)*256 + t;
        tp1[o] = tanhf(acc[j]);
    }
}

__global__ void k_z2(const float* __restrict__ tp1, const float* __restrict__ wv,
                     const float* __restrict__ Wd1, float* __restrict__ z2T) {
    __shared__ float coef[16*256];
    int n0 = blockIdx.x * 16, t = threadIdx.x;
    #pragma unroll
    for (int i = 0; i < 16; i++) {
        int f = t + i*256;
        coef[f] = tp1[n0*256 + f] * wv[f & 255];
    }
    __syncthreads();
    float acc[16];
    #pragma unroll
    for (int j = 0; j < 16; j++) acc[j] = 0.f;
    for (int m = 0; m < 256; m++) {
        float w = Wd1[m*256 + t];
        #pragma unroll
        for (int j = 0; j < 16; j++) acc[j] += w * coef[j*256 + m];
    }
    float wvt = wv[t];
    for (int j = 0; j < 16; j++) z2T[(n0+j)*256 + t] = wvt + 0.5f*acc[j];
}

__global__ void k_z1(const float* __restrict__ tp0, const float* __restrict__ z2T,
                     const float* __restrict__ Wd0, float* __restrict__ z1T) {
    __shared__ float coef[16*256];
    int n0 = blockIdx.x * 16, t = threadIdx.x;
    #pragma unroll
    for (int i = 0; i < 16; i++) {
        int f = t + i*256;
        coef[f] = tp0[n0*256 + f] * z2T[n0*256 + f];
    }
    __syncthreads();
    float acc[16];
    #pragma unroll
    for (int j = 0; j < 16; j++) acc[j] = 0.f;
    for (int m = 0; m < 256; m++) {
        float w = Wd0[m*256 + t];
        #pragma unroll
        for (int j = 0; j < 16; j++) acc[j] += w * coef[j*256 + m];
    }
    for (int j = 0; j < 16; j++) {
        int o = (n0+j)*256 + t;
        z1T[o] = z2T[o] + 0.5f*acc[j];
    }
}

__global__ void k_grad(const float* __restrict__ tanhopen, const float* __restrict__ z1T,
                       const float* __restrict__ W0, const float* __restrict__ symA,
                       const float* __restrict__ x, const float* __restrict__ cw,
                       float* __restrict__ out) {
    __shared__ float coef[16*256];
    __shared__ float sa[64*64];
    __shared__ float xs[16*64];
    __shared__ float cws[64];
    int n0 = blockIdx.x * 16, t = threadIdx.x;
    #pragma unroll
    for (int i = 0; i < 16; i++) {
        int f = t + i*256;
        coef[f] = tanhopen[n0*256 + f] * z1T[n0*256 + f];
        sa[f] = symA[f];
    }
    #pragma unroll
    for (int i = 0; i < 4; i++) { int f = t + i*256; xs[f] = x[n0*64 + f]; }
    if (t < 64) cws[t] = cw[t];
    __syncthreads();
    int c = t & 63, jj = t >> 6;
    float acc[4] = {0.f, 0.f, 0.f, 0.f};
    for (int m = 0; m < 256; m++) {
        float w0v = W0[m*64 + c];
        #pragma unroll
        for (int jb = 0; jb < 4; jb++) acc[jb] += coef[(jj + jb*4)*256 + m] * w0v;
    }
    for (int jb = 0; jb < 4; jb++) {
        int j = jj + jb*4;
        float g2 = 0.f;
        for (int jd = 0; jd < 64; jd++) g2 += sa[jd*64 + c] * xs[j*64 + jd];
        out[(n0+j)*64 + c] = acc[jb] + g2 + cws[c];
    }
}

// ---------------- heavy per-example Jacobian kernel (split-bf16 MFMA) ----------------
// One block per example, 4 waves. Computes KJ^T = Jac^T @ Wd^T per layer with
// A = Jac^T (64x256, hi/lo bf16 in LDS), B = Wd row-major hi/lo bf16 (global).
// 16x16x32 MFMA; wave w owns a-tiles 4w..4w+3 (a in [64w,64w+64)), all 4 d-tiles.
// C layout: col(a) = lane&15, row(d) = (lane>>4)*4 + reg  [m89-verified].
__global__ __launch_bounds__(256, 2) void k_heavy_mfma(
        const float* __restrict__ tanhopen, const float* __restrict__ tp0,
        const float* __restrict__ tp1, const float* __restrict__ z2T,
        const float* __restrict__ z1T, const float* __restrict__ wv,
        const float* __restrict__ W0T,
        const unsigned short* __restrict__ WdHi, const unsigned short* __restrict__ WdLo,
        const float* __restrict__ ksq, const float* __restrict__ trace,
        float* __restrict__ outTrH) {
    __shared__ __align__(16) unsigned short Jhi[64*JSTR];
    __shared__ __align__(16) unsigned short Jlo[64*JSTR];
    __shared__ float tp0s[256], w1s[256], w2s[256];
    __shared__ float red[4];
    int n = blockIdx.x, t = threadIdx.x;
    int lane = t & 63, w = t >> 6, l15 = lane & 15, lg = lane >> 4;

    float sv   = tanhopen[n*256 + t];
    float tp0v = tp0[n*256 + t];
    float tp1v = tp1[n*256 + t];
    tp0s[t] = tp0v;
    w1s[t]  = (1.f - tp0v*tp0v) * z2T[n*256 + t];
    w2s[t]  = (1.f - tp1v*tp1v) * wv[t];
    float tot = (1.f - sv*sv) * z1T[n*256 + t] * ksq[t];   // trH layer-0 partial (m=t)

    // build JacT[d][m] = W0T[d][m]*s[m], row 63 zero; thread t owns column m=t
    for (int d = 0; d < 63; ++d) {
        float v = W0T[d*256 + t] * sv;
        unsigned short h = f2bfu(v);
        Jhi[d*JSTR + t] = h;
        Jlo[d*JSTR + t] = f2bfu(v - bfu2f(h));
    }
    Jhi[63*JSTR + t] = 0;
    Jlo[63*JSTR + t] = 0;
    __syncthreads();

    floatx4 acc[4][4];

    // ---------------- layer 0: KJ1^T ----------------
    #pragma unroll
    for (int c = 0; c < 4; ++c)
        #pragma unroll
        for (int j = 0; j < 4; ++j)
            acc[c][j] = (floatx4){0.f, 0.f, 0.f, 0.f};

    #pragma unroll 2
    for (int kk = 0; kk < 8; ++kk) {
        int ko = kk*32 + lg*8;
        short8 Ah[4], Al[4], Bh[4], Bl[4];
        #pragma unroll
        for (int c = 0; c < 4; ++c) {
            int off = (c*16 + l15)*JSTR + ko;
            Ah[c] = *reinterpret_cast<const short8*>(&Jhi[off]);
            Al[c] = *reinterpret_cast<const short8*>(&Jlo[off]);
        }
        #pragma unroll
        for (int j = 0; j < 4; ++j) {
            int a = (w*4 + j)*16 + l15;
            Bh[j] = *reinterpret_cast<const short8*>(WdHi + a*256 + ko);
            Bl[j] = *reinterpret_cast<const short8*>(WdLo + a*256 + ko);
        }
        #pragma unroll
        for (int c = 0; c < 4; ++c)
            #pragma unroll
            for (int j = 0; j < 4; ++j) {
                acc[c][j] = __builtin_amdgcn_mfma_f32_16x16x32_bf16(Ah[c], Bh[j], acc[c][j], 0, 0, 0);
                acc[c][j] = __builtin_amdgcn_mfma_f32_16x16x32_bf16(Ah[c], Bl[j], acc[c][j], 0, 0, 0);
                acc[c][j] = __builtin_amdgcn_mfma_f32_16x16x32_bf16(Al[c], Bh[j], acc[c][j], 0, 0, 0);
            }
    }
    __syncthreads();   // all reads of JacT done before update writes

    // trH layer-1 term + Jac update: JacT[d][a] += 0.5*tp0[a]*KJ1T[d][a]
    {
        float w1a[4], tp0a[4]; int abase[4];
        #pragma unroll
        for (int j = 0; j < 4; ++j) {
            int a = (w*4 + j)*16 + l15;
            abase[j] = a;
            w1a[j]  = w1s[a];
            tp0a[j] = 0.5f * tp0s[a];
        }
        #pragma unroll
        for (int c = 0; c < 4; ++c)
            #pragma unroll
            for (int r = 0; r < 4; ++r) {
                int d = c*16 + lg*4 + r;
                int row = d*JSTR;
                #pragma unroll
                for (int j = 0; j < 4; ++j) {
                    float v = acc[c][j][r];
                    tot += 0.5f * w1a[j] * v * v;
                    int off = row + abase[j];
                    float old = bfu2f(Jhi[off]) + bfu2f(Jlo[off]);
                    float nw = old + tp0a[j] * v;
                    unsigned short h = f2bfu(nw);
                    Jhi[off] = h;
                    Jlo[off] = f2bfu(nw - bfu2f(h));
                }
            }
    }
    __syncthreads();   // updates visible before layer-1 reads

    // ---------------- layer 1: KJ2^T ----------------
    #pragma unroll
    for (int c = 0; c < 4; ++c)
        #pragma unroll
        for (int j = 0; j < 4; ++j)
            acc[c][j] = (floatx4){0.f, 0.f, 0.f, 0.f};

    const unsigned short* W1h = WdHi + 65536;
    const unsigned short* W1l = WdLo + 65536;
    #pragma unroll 2
    for (int kk = 0; kk < 8; ++kk) {
        int ko = kk*32 + lg*8;
        short8 Ah[4], Al[4], Bh[4], Bl[4];
        #pragma unroll
        for (int c = 0; c < 4; ++c) {
            int off = (c*16 + l15)*JSTR + ko;
            Ah[c] = *reinterpret_cast<const short8*>(&Jhi[off]);
            Al[c] = *reinterpret_cast<const short8*>(&Jlo[off]);
        }
        #pragma unroll
        for (int j = 0; j < 4; ++j) {
            int a = (w*4 + j)*16 + l15;
            Bh[j] = *reinterpret_cast<const short8*>(W1h + a*256 + ko);
            Bl[j] = *reinterpret_cast<const short8*>(W1l + a*256 + ko);
        }
        #pragma unroll
        for (int c = 0; c < 4; ++c)
            #pragma unroll
            for (int j = 0; j < 4; ++j) {
                acc[c][j] = __builtin_amdgcn_mfma_f32_16x16x32_bf16(Ah[c], Bh[j], acc[c][j], 0, 0, 0);
                acc[c][j] = __builtin_amdgcn_mfma_f32_16x16x32_bf16(Ah[c], Bl[j], acc[c][j], 0, 0, 0);
                acc[c][j] = __builtin_amdgcn_mfma_f32_16x16x32_bf16(Al[c], Bh[j], acc[c][j], 0, 0, 0);
            }
    }

    // trH layer-2 term
    {
        float w2a[4];
        #pragma unroll
        for (int j = 0; j < 4; ++j) w2a[j] = w2s[(w*4 + j)*16 + l15];
        #pragma unroll
        for (int c = 0; c < 4; ++c)
            #pragma unroll
            for (int j = 0; j < 4; ++j)
                #pragma unroll
                for (int r = 0; r < 4; ++r) {
                    float v = acc[c][j][r];
                    tot += 0.5f * w2a[j] * v * v;
                }
    }

    // reduce 256 -> 1
    for (int off = 32; off; off >>= 1) tot += __shfl_down(tot, off, 64);
    if (lane == 0) red[w] = tot;
    __syncthreads();
    if (t == 0) outTrH[n] = red[0] + red[1] + red[2] + red[3] + trace[0];
}

// ---------------- launcher ----------------

extern "C" void kernel_launch(void* const* d_in, const int* in_sizes, int n_in,
                              void* d_out, int out_size, void* d_ws, size_t ws_size,
                              hipStream_t stream) {
    const float* x   = (const float*)d_in[0];   // 4096*64
    const float* W0  = (const float*)d_in[1];   // 256*64
    const float* b0  = (const float*)d_in[2];   // 256
    const float* Wd  = (const float*)d_in[3];   // 2*256*256
    const float* bd  = (const float*)d_in[4];   // 2*256
    const float* wv  = (const float*)d_in[5];   // 256
    const float* A   = (const float*)d_in[6];   // 10*64
    const float* cw  = (const float*)d_in[7];   // 64
    float* out = (float*)d_out;
    float* ws  = (float*)d_ws;

    float* tanhopen = ws;               // NM
    float* u0   = tanhopen + NM;        // NM (reused for WdHi/WdLo after k_pre0)
    float* u1   = u0 + NM;              // NM
    float* tp0  = u1 + NM;              // NM
    float* tp1  = tp0 + NM;             // NM
    float* z2T  = tp1 + NM;             // NM
    float* z1T  = z2T + NM;             // NM
    float* Wd0T = z1T + NM;             // 65536
    float* Wd1T = Wd0T + 65536;         // 65536
    float* W0T  = Wd1T + 65536;         // 16384
    float* symA = W0T + 16384;          // 4096
    float* ksq  = symA + 4096;          // 256
    float* trace= ksq + 256;            // 1

    // hi/lo split of Wd lives in u0's buffer (dead after k_pre0): 131072*2 ushorts
    unsigned short* WdHi = (unsigned short*)u0;
    unsigned short* WdLo = WdHi + 131072;

    const float* Wd0 = Wd;
    const float* Wd1 = Wd + 65536;

    k_symA<<<16, 256, 0, stream>>>(A, symA);
    k_transpose<<<256, 256, 0, stream>>>(Wd0, Wd0T, 256, 256);
    k_transpose<<<256, 256, 0, stream>>>(Wd1, Wd1T, 256, 256);
    k_transpose<<<64, 256, 0, stream>>>(W0, W0T, 256, 64);
    k_misc<<<1, 256, 0, stream>>>(W0, A, ksq, trace);

    k_opening<<<NEX/16, 256, 0, stream>>>(x, W0T, b0, tanhopen, u0);
    k_pre0<<<NEX/16, 256, 0, stream>>>(u0, Wd0T, bd, tp0, u1);
    k_split<<<512, 256, 0, stream>>>(Wd, WdHi, WdLo);   // after k_pre0: u0 is dead
    k_pre1<<<NEX/16, 256, 0, stream>>>(u1, Wd1T, bd + 256, tp1);
    k_z2<<<NEX/16, 256, 0, stream>>>(tp1, wv, Wd1, z2T);
    k_z1<<<NEX/16, 256, 0, stream>>>(tp0, z2T, Wd0, z1T);
    k_grad<<<NEX/16, 256, 0, stream>>>(tanhopen, z1T, W0, symA, x, cw, out);
    k_heavy_mfma<<<NEX, 256, 0, stream>>>(tanhopen, tp0, tp1, z2T, z1T, wv,
                                          W0T, WdHi, WdLo, ksq, trace, out + NEX*64);
}

// Round 3
// 430.297 us; speedup vs baseline: 3.9235x; 1.1073x over previous
//
#include <hip/hip_runtime.h>
#include <hip/hip_bf16.h>

#define NEX 4096
#define M   256
#define NM  (NEX*M)

typedef __attribute__((ext_vector_type(8))) short short8;
typedef __attribute__((ext_vector_type(4))) float floatx4;

__device__ inline unsigned short f2bfu(float x) {
    __hip_bfloat16 h = __float2bfloat16(x);
    union { __hip_bfloat16 b; unsigned short u; } cv; cv.b = h;
    return cv.u;
}
__device__ inline float bfu2f(unsigned short u) {
    union { unsigned short u; __hip_bfloat16 b; } cv; cv.u = u;
    return __bfloat162float(cv.b);
}

// swizzled element offset for [64][256] bf16 LDS tile, 16B-chunk XOR
__device__ inline int swz(int row, int col) {
    return row*256 + ((((col >> 3) ^ (row & 7)) << 3) | (col & 7));
}

// ---------------- fused prep kernel ----------------
// b in [0,512): split Wd -> hi/lo bf16
// b in [512,768): Wd0T ; [768,1024): Wd1T ; [1024,1088): W0T
// b == 1088: ksq + trace ; b in [1089,1105): symA
__global__ void k_prep(const float* __restrict__ Wd, const float* __restrict__ W0,
                       const float* __restrict__ A,
                       unsigned short* __restrict__ WdHi, unsigned short* __restrict__ WdLo,
                       float* __restrict__ Wd0T, float* __restrict__ Wd1T,
                       float* __restrict__ W0T, float* __restrict__ symA,
                       float* __restrict__ ksq, float* __restrict__ trace) {
    int b = blockIdx.x, t = threadIdx.x;
    if (b < 512) {
        int idx = b*256 + t;
        float x = Wd[idx];
        unsigned short h = f2bfu(x);
        WdHi[idx] = h;
        WdLo[idx] = f2bfu(x - bfu2f(h));
    } else if (b < 768) {
        int idx = (b-512)*256 + t;          // dst index c*256+r
        int c = idx >> 8, r = idx & 255;
        Wd0T[idx] = Wd[r*256 + c];
    } else if (b < 1024) {
        int idx = (b-768)*256 + t;
        int c = idx >> 8, r = idx & 255;
        Wd1T[idx] = Wd[65536 + r*256 + c];
    } else if (b < 1088) {
        int idx = (b-1024)*256 + t;         // 16384 entries: c*256+r, c<64
        int c = idx >> 8, r = idx & 255;
        W0T[idx] = W0[r*64 + c];
    } else if (b == 1088) {
        float s = 0.f;
        for (int dd = 0; dd < 63; dd++) { float v = W0[t*64+dd]; s += v*v; }
        ksq[t] = s;
        float p = 0.f;
        for (int idx = t; idx < 630; idx += 256) {
            int r = idx / 63, i = idx % 63;
            float v = A[r*64+i]; p += v*v;
        }
        for (int off = 32; off; off >>= 1) p += __shfl_down(p, off, 64);
        __shared__ float red[4];
        if ((t & 63) == 0) red[t >> 6] = p;
        __syncthreads();
        if (t == 0) trace[0] = red[0]+red[1]+red[2]+red[3];
    } else {
        int idx = (b-1089)*256 + t;         // 4096 entries
        int i = idx >> 6, j = idx & 63;
        float s = 0.f;
        #pragma unroll
        for (int r = 0; r < 10; r++) s += A[r*64+i] * A[r*64+j];
        symA[idx] = s;
    }
}

// ---------------- fused forward chain: opening + pre0 + pre1 ----------------
// 8 examples per block, 512 blocks, 256 threads (thread t owns unit m=t)
__global__ void k_fwd(const float* __restrict__ x, const float* __restrict__ W0T,
                      const float* __restrict__ b0, const float* __restrict__ Wd0T,
                      const float* __restrict__ Wd1T, const float* __restrict__ bd,
                      float* __restrict__ tanhopen, float* __restrict__ tp0,
                      float* __restrict__ tp1) {
    __shared__ float xs[8*64];
    __shared__ float u0s[8*256];
    __shared__ float u1s[8*256];
    int n0 = blockIdx.x * 8, t = threadIdx.x;
    #pragma unroll
    for (int i = 0; i < 2; i++) { int f = t + i*256; xs[f] = x[n0*64 + f]; }
    __syncthreads();
    float acc[8];
    // ---- opening ----
    float b = b0[t];
    #pragma unroll
    for (int j = 0; j < 8; j++) acc[j] = b;
    for (int c = 0; c < 64; c++) {
        float w = W0T[c*256 + t];
        #pragma unroll
        for (int j = 0; j < 8; j++) acc[j] += w * xs[j*64 + c];
    }
    #pragma unroll
    for (int j = 0; j < 8; j++) {
        float p = acc[j];
        tanhopen[(n0+j)*256 + t] = tanhf(p);
        float a = fabsf(p);
        u0s[j*256 + t] = a + log1pf(expf(-2.f*a));
    }
    __syncthreads();
    // ---- pre0 ----
    b = bd[t];
    #pragma unroll
    for (int j = 0; j < 8; j++) acc[j] = b;
    for (int k = 0; k < 256; k++) {
        float w = Wd0T[k*256 + t];
        #pragma unroll
        for (int j = 0; j < 8; j++) acc[j] += w * u0s[j*256 + k];
    }
    #pragma unroll
    for (int j = 0; j < 8; j++) {
        float p = acc[j];
        tp0[(n0+j)*256 + t] = tanhf(p);
        float a = fabsf(p);
        u1s[j*256 + t] = u0s[j*256 + t] + 0.5f*(a + log1pf(expf(-2.f*a)));
    }
    __syncthreads();
    // ---- pre1 ----
    b = bd[256 + t];
    #pragma unroll
    for (int j = 0; j < 8; j++) acc[j] = b;
    for (int k = 0; k < 256; k++) {
        float w = Wd1T[k*256 + t];
        #pragma unroll
        for (int j = 0; j < 8; j++) acc[j] += w * u1s[j*256 + k];
    }
    #pragma unroll
    for (int j = 0; j < 8; j++) tp1[(n0+j)*256 + t] = tanhf(acc[j]);
}

// ---------------- fused backward chain: z2 + z1 + grad ----------------
// 8 examples per block, 512 blocks, 256 threads
__global__ void k_bwd(const float* __restrict__ tanhopen, const float* __restrict__ tp0,
                      const float* __restrict__ tp1, const float* __restrict__ wv,
                      const float* __restrict__ Wd, const float* __restrict__ W0,
                      const float* __restrict__ symA, const float* __restrict__ x,
                      const float* __restrict__ cw,
                      float* __restrict__ z2T, float* __restrict__ z1T,
                      float* __restrict__ out) {
    __shared__ float coefs[8*256];
    __shared__ float z2s[8*256];
    __shared__ float sa[64*64];
    __shared__ float xs[8*64];
    __shared__ float cws[64];
    const float* Wd0 = Wd;
    const float* Wd1 = Wd + 65536;
    int n0 = blockIdx.x * 8, t = threadIdx.x;
    float wvt = wv[t];
    // coef = tanh(pre1)*wv
    #pragma unroll
    for (int j = 0; j < 8; j++) coefs[j*256 + t] = tp1[(n0+j)*256 + t] * wvt;
    #pragma unroll
    for (int i = 0; i < 16; i++) { int f = t + i*256; sa[f] = symA[f]; }
    #pragma unroll
    for (int i = 0; i < 2; i++) { int f = t + i*256; xs[f] = x[n0*64 + f]; }
    if (t < 64) cws[t] = cw[t];
    __syncthreads();
    float acc[8];
    // ---- z2 ----
    #pragma unroll
    for (int j = 0; j < 8; j++) acc[j] = 0.f;
    for (int m = 0; m < 256; m++) {
        float w = Wd1[m*256 + t];
        #pragma unroll
        for (int j = 0; j < 8; j++) acc[j] += w * coefs[j*256 + m];
    }
    #pragma unroll
    for (int j = 0; j < 8; j++) {
        float v = wvt + 0.5f*acc[j];
        z2s[j*256 + t] = v;
        z2T[(n0+j)*256 + t] = v;
    }
    __syncthreads();
    // coef2 = tanh(pre0)*z2
    #pragma unroll
    for (int j = 0; j < 8; j++) coefs[j*256 + t] = tp0[(n0+j)*256 + t] * z2s[j*256 + t];
    __syncthreads();
    // ---- z1 ---- (in-place into z2s: each thread only reads its own slot)
    #pragma unroll
    for (int j = 0; j < 8; j++) acc[j] = 0.f;
    for (int m = 0; m < 256; m++) {
        float w = Wd0[m*256 + t];
        #pragma unroll
        for (int j = 0; j < 8; j++) acc[j] += w * coefs[j*256 + m];
    }
    #pragma unroll
    for (int j = 0; j < 8; j++) {
        float v = z2s[j*256 + t] + 0.5f*acc[j];
        z2s[j*256 + t] = v;               // now holds z1
        z1T[(n0+j)*256 + t] = v;
    }
    __syncthreads();
    // coef3 = tanhopen * z1
    #pragma unroll
    for (int j = 0; j < 8; j++) coefs[j*256 + t] = tanhopen[(n0+j)*256 + t] * z2s[j*256 + t];
    __syncthreads();
    // ---- grad ----
    int c = t & 63, jj = t >> 6;
    float g[2] = {0.f, 0.f};
    for (int m = 0; m < 256; m++) {
        float w0v = W0[m*64 + c];
        #pragma unroll
        for (int jb = 0; jb < 2; jb++) g[jb] += coefs[(jj + jb*4)*256 + m] * w0v;
    }
    #pragma unroll
    for (int jb = 0; jb < 2; jb++) {
        int j = jj + jb*4;
        float g2 = 0.f;
        for (int jd = 0; jd < 64; jd++) g2 += sa[jd*64 + c] * xs[j*64 + jd];
        out[(n0+j)*64 + c] = g[jb] + g2 + cws[c];
    }
}

// ---------------- heavy per-example Jacobian kernel (bf16-A, hi/lo-B MFMA) ----------------
// One block per example, 4 waves, 4 blocks/CU (LDS ~36 KB, VGPR <=128).
// KJ^T = Jac^T @ Wd^T : A = Jac^T (64x256 bf16, swizzled LDS), B = Wd hi/lo (global).
// 16x16x32 MFMA; wave w owns a-tiles 4w..4w+3, all 4 d-tiles.
// C layout: col(a)=lane&15, row(d)=(lane>>4)*4+reg.
__global__ __launch_bounds__(256, 4) void k_heavy_mfma(
        const float* __restrict__ tanhopen, const float* __restrict__ tp0,
        const float* __restrict__ tp1, const float* __restrict__ z2T,
        const float* __restrict__ z1T, const float* __restrict__ wv,
        const float* __restrict__ W0T,
        const unsigned short* __restrict__ WdHi, const unsigned short* __restrict__ WdLo,
        const float* __restrict__ ksq, const float* __restrict__ trace,
        float* __restrict__ outTrH) {
    __shared__ __align__(16) unsigned short Jhi[64*256];
    __shared__ float tp0s[256], w1s[256], w2s[256];
    __shared__ float red[4];
    int n = blockIdx.x, t = threadIdx.x;
    int lane = t & 63, w = t >> 6, l15 = lane & 15, lg = lane >> 4;

    float sv   = tanhopen[n*256 + t];
    float tp0v = tp0[n*256 + t];
    float tp1v = tp1[n*256 + t];
    tp0s[t] = tp0v;
    w1s[t]  = (1.f - tp0v*tp0v) * z2T[n*256 + t];
    w2s[t]  = (1.f - tp1v*tp1v) * wv[t];
    float tot = (1.f - sv*sv) * z1T[n*256 + t] * ksq[t];   // trH layer-0 partial (m=t)

    // build JacT[d][m] = W0T[d][m]*s[m] (bf16), row 63 zero; thread t owns col m=t
    #pragma unroll 4
    for (int d = 0; d < 63; ++d) {
        float v = W0T[d*256 + t] * sv;
        Jhi[swz(d, t)] = f2bfu(v);
    }
    Jhi[swz(63, t)] = 0;
    __syncthreads();

    floatx4 acc[4][4];

    // ---------------- layer 0: KJ1^T ----------------
    #pragma unroll
    for (int c = 0; c < 4; ++c)
        #pragma unroll
        for (int j = 0; j < 4; ++j)
            acc[c][j] = (floatx4){0.f, 0.f, 0.f, 0.f};

    #pragma unroll 2
    for (int kk = 0; kk < 8; ++kk) {
        int ko = kk*32 + lg*8;
        short8 Ah[4];
        #pragma unroll
        for (int c = 0; c < 4; ++c) {
            int row = c*16 + l15;
            Ah[c] = *reinterpret_cast<const short8*>(&Jhi[swz(row, ko)]);
        }
        #pragma unroll
        for (int j = 0; j < 4; ++j) {
            int a = (w*4 + j)*16 + l15;
            short8 Bh = *reinterpret_cast<const short8*>(WdHi + a*256 + ko);
            short8 Bl = *reinterpret_cast<const short8*>(WdLo + a*256 + ko);
            #pragma unroll
            for (int c = 0; c < 4; ++c) {
                acc[c][j] = __builtin_amdgcn_mfma_f32_16x16x32_bf16(Ah[c], Bh, acc[c][j], 0, 0, 0);
                acc[c][j] = __builtin_amdgcn_mfma_f32_16x16x32_bf16(Ah[c], Bl, acc[c][j], 0, 0, 0);
            }
        }
    }
    __syncthreads();   // all layer-0 reads of JacT done before update writes

    // trH layer-1 term + Jac update: JacT[d][a] += 0.5*tp0[a]*KJ1T[d][a]
    {
        float w1a[4], tp0a[4]; int aidx[4];
        #pragma unroll
        for (int j = 0; j < 4; ++j) {
            int a = (w*4 + j)*16 + l15;
            aidx[j] = a;
            w1a[j]  = w1s[a];
            tp0a[j] = 0.5f * tp0s[a];
        }
        #pragma unroll
        for (int c = 0; c < 4; ++c)
            #pragma unroll
            for (int r = 0; r < 4; ++r) {
                int d = c*16 + lg*4 + r;
                #pragma unroll
                for (int j = 0; j < 4; ++j) {
                    float v = acc[c][j][r];
                    tot += 0.5f * w1a[j] * v * v;
                    int off = swz(d, aidx[j]);
                    Jhi[off] = f2bfu(bfu2f(Jhi[off]) + tp0a[j] * v);
                }
            }
    }
    __syncthreads();   // updates visible before layer-1 reads

    // ---------------- layer 1: KJ2^T ----------------
    #pragma unroll
    for (int c = 0; c < 4; ++c)
        #pragma unroll
        for (int j = 0; j < 4; ++j)
            acc[c][j] = (floatx4){0.f, 0.f, 0.f, 0.f};

    const unsigned short* W1h = WdHi + 65536;
    const unsigned short* W1l = WdLo + 65536;
    #pragma unroll 2
    for (int kk = 0; kk < 8; ++kk) {
        int ko = kk*32 + lg*8;
        short8 Ah[4];
        #pragma unroll
        for (int c = 0; c < 4; ++c) {
            int row = c*16 + l15;
            Ah[c] = *reinterpret_cast<const short8*>(&Jhi[swz(row, ko)]);
        }
        #pragma unroll
        for (int j = 0; j < 4; ++j) {
            int a = (w*4 + j)*16 + l15;
            short8 Bh = *reinterpret_cast<const short8*>(W1h + a*256 + ko);
            short8 Bl = *reinterpret_cast<const short8*>(W1l + a*256 + ko);
            #pragma unroll
            for (int c = 0; c < 4; ++c) {
                acc[c][j] = __builtin_amdgcn_mfma_f32_16x16x32_bf16(Ah[c], Bh, acc[c][j], 0, 0, 0);
                acc[c][j] = __builtin_amdgcn_mfma_f32_16x16x32_bf16(Ah[c], Bl, acc[c][j], 0, 0, 0);
            }
        }
    }

    // trH layer-2 term
    {
        float w2a[4];
        #pragma unroll
        for (int j = 0; j < 4; ++j) w2a[j] = w2s[(w*4 + j)*16 + l15];
        #pragma unroll
        for (int c = 0; c < 4; ++c)
            #pragma unroll
            for (int j = 0; j < 4; ++j)
                #pragma unroll
                for (int r = 0; r < 4; ++r) {
                    float v = acc[c][j][r];
                    tot += 0.5f * w2a[j] * v * v;
                }
    }

    // reduce 256 -> 1
    for (int off = 32; off; off >>= 1) tot += __shfl_down(tot, off, 64);
    if (lane == 0) red[w] = tot;
    __syncthreads();
    if (t == 0) outTrH[n] = red[0] + red[1] + red[2] + red[3] + trace[0];
}

// ---------------- launcher ----------------

extern "C" void kernel_launch(void* const* d_in, const int* in_sizes, int n_in,
                              void* d_out, int out_size, void* d_ws, size_t ws_size,
                              hipStream_t stream) {
    const float* x   = (const float*)d_in[0];   // 4096*64
    const float* W0  = (const float*)d_in[1];   // 256*64
    const float* b0  = (const float*)d_in[2];   // 256
    const float* Wd  = (const float*)d_in[3];   // 2*256*256
    const float* bd  = (const float*)d_in[4];   // 2*256
    const float* wv  = (const float*)d_in[5];   // 256
    const float* A   = (const float*)d_in[6];   // 10*64
    const float* cw  = (const float*)d_in[7];   // 64
    float* out = (float*)d_out;
    float* ws  = (float*)d_ws;

    float* tanhopen = ws;               // NM
    float* tp0  = tanhopen + NM;        // NM
    float* tp1  = tp0 + NM;             // NM
    float* z2T  = tp1 + NM;             // NM
    float* z1T  = z2T + NM;             // NM
    float* Wd0T = z1T + NM;             // 65536
    float* Wd1T = Wd0T + 65536;         // 65536
    float* W0T  = Wd1T + 65536;         // 16384
    float* symA = W0T + 16384;          // 4096
    float* ksq  = symA + 4096;          // 256
    float* trace= ksq + 256;            // 1
    unsigned short* WdHi = (unsigned short*)(trace + 1);  // 131072 ushorts
    unsigned short* WdLo = WdHi + 131072;                 // 131072 ushorts

    k_prep<<<1105, 256, 0, stream>>>(Wd, W0, A, WdHi, WdLo, Wd0T, Wd1T, W0T,
                                     symA, ksq, trace);
    k_fwd<<<NEX/8, 256, 0, stream>>>(x, W0T, b0, Wd0T, Wd1T, bd,
                                     tanhopen, tp0, tp1);
    k_bwd<<<NEX/8, 256, 0, stream>>>(tanhopen, tp0, tp1, wv, Wd, W0, symA, x, cw,
                                     z2T, z1T, out);
    k_heavy_mfma<<<NEX, 256, 0, stream>>>(tanhopen, tp0, tp1, z2T, z1T, wv,
                                          W0T, WdHi, WdLo, ksq, trace, out + NEX*64);
}

// Round 4
// 344.118 us; speedup vs baseline: 4.9061x; 1.2504x over previous
//
#include <hip/hip_runtime.h>
#include <hip/hip_bf16.h>

#define NEX 4096
#define M   256
#define NM  (NEX*M)

typedef __attribute__((ext_vector_type(8))) short short8;
typedef __attribute__((ext_vector_type(4))) float floatx4;

__device__ inline unsigned short f2bfu(float x) {
    __hip_bfloat16 h = __float2bfloat16(x);
    union { __hip_bfloat16 b; unsigned short u; } cv; cv.b = h;
    return cv.u;
}
__device__ inline float bfu2f(unsigned short u) {
    union { unsigned short u; __hip_bfloat16 b; } cv; cv.u = u;
    return __bfloat162float(cv.b);
}

// swizzled element offset for [64][256] bf16 LDS tile, 16B-chunk XOR
__device__ inline int swz(int row, int col) {
    return row*256 + ((((col >> 3) ^ (row & 7)) << 3) | (col & 7));
}

// ---------------- fused prep kernel ----------------
__global__ void k_prep(const float* __restrict__ Wd, const float* __restrict__ W0,
                       const float* __restrict__ A,
                       unsigned short* __restrict__ WdHi, unsigned short* __restrict__ WdLo,
                       float* __restrict__ Wd0T, float* __restrict__ Wd1T,
                       float* __restrict__ W0T, float* __restrict__ symA,
                       float* __restrict__ ksq, float* __restrict__ trace) {
    int b = blockIdx.x, t = threadIdx.x;
    if (b < 512) {
        int idx = b*256 + t;
        float x = Wd[idx];
        unsigned short h = f2bfu(x);
        WdHi[idx] = h;
        WdLo[idx] = f2bfu(x - bfu2f(h));
    } else if (b < 768) {
        int idx = (b-512)*256 + t;          // dst index c*256+r
        int c = idx >> 8, r = idx & 255;
        Wd0T[idx] = Wd[r*256 + c];
    } else if (b < 1024) {
        int idx = (b-768)*256 + t;
        int c = idx >> 8, r = idx & 255;
        Wd1T[idx] = Wd[65536 + r*256 + c];
    } else if (b < 1088) {
        int idx = (b-1024)*256 + t;         // 16384 entries: c*256+r, c<64
        int c = idx >> 8, r = idx & 255;
        W0T[idx] = W0[r*64 + c];
    } else if (b == 1088) {
        float s = 0.f;
        for (int dd = 0; dd < 63; dd++) { float v = W0[t*64+dd]; s += v*v; }
        ksq[t] = s;
        float p = 0.f;
        for (int idx = t; idx < 630; idx += 256) {
            int r = idx / 63, i = idx % 63;
            float v = A[r*64+i]; p += v*v;
        }
        for (int off = 32; off; off >>= 1) p += __shfl_down(p, off, 64);
        __shared__ float red[4];
        if ((t & 63) == 0) red[t >> 6] = p;
        __syncthreads();
        if (t == 0) trace[0] = red[0]+red[1]+red[2]+red[3];
    } else {
        int idx = (b-1089)*256 + t;         // 4096 entries
        int i = idx >> 6, j = idx & 63;
        float s = 0.f;
        #pragma unroll
        for (int r = 0; r < 10; r++) s += A[r*64+i] * A[r*64+j];
        symA[idx] = s;
    }
}

// ---------------- fused forward chain: opening + pre0 + pre1 ----------------
__global__ void k_fwd(const float* __restrict__ x, const float* __restrict__ W0T,
                      const float* __restrict__ b0, const float* __restrict__ Wd0T,
                      const float* __restrict__ Wd1T, const float* __restrict__ bd,
                      float* __restrict__ tanhopen, float* __restrict__ tp0,
                      float* __restrict__ tp1) {
    __shared__ float xs[8*64];
    __shared__ float u0s[8*256];
    __shared__ float u1s[8*256];
    int n0 = blockIdx.x * 8, t = threadIdx.x;
    #pragma unroll
    for (int i = 0; i < 2; i++) { int f = t + i*256; xs[f] = x[n0*64 + f]; }
    __syncthreads();
    float acc[8];
    float b = b0[t];
    #pragma unroll
    for (int j = 0; j < 8; j++) acc[j] = b;
    for (int c = 0; c < 64; c++) {
        float w = W0T[c*256 + t];
        #pragma unroll
        for (int j = 0; j < 8; j++) acc[j] += w * xs[j*64 + c];
    }
    #pragma unroll
    for (int j = 0; j < 8; j++) {
        float p = acc[j];
        tanhopen[(n0+j)*256 + t] = tanhf(p);
        float a = fabsf(p);
        u0s[j*256 + t] = a + log1pf(expf(-2.f*a));
    }
    __syncthreads();
    b = bd[t];
    #pragma unroll
    for (int j = 0; j < 8; j++) acc[j] = b;
    for (int k = 0; k < 256; k++) {
        float w = Wd0T[k*256 + t];
        #pragma unroll
        for (int j = 0; j < 8; j++) acc[j] += w * u0s[j*256 + k];
    }
    #pragma unroll
    for (int j = 0; j < 8; j++) {
        float p = acc[j];
        tp0[(n0+j)*256 + t] = tanhf(p);
        float a = fabsf(p);
        u1s[j*256 + t] = u0s[j*256 + t] + 0.5f*(a + log1pf(expf(-2.f*a)));
    }
    __syncthreads();
    b = bd[256 + t];
    #pragma unroll
    for (int j = 0; j < 8; j++) acc[j] = b;
    for (int k = 0; k < 256; k++) {
        float w = Wd1T[k*256 + t];
        #pragma unroll
        for (int j = 0; j < 8; j++) acc[j] += w * u1s[j*256 + k];
    }
    #pragma unroll
    for (int j = 0; j < 8; j++) tp1[(n0+j)*256 + t] = tanhf(acc[j]);
}

// ---------------- fused backward chain: z2 + z1 + grad ----------------
__global__ void k_bwd(const float* __restrict__ tanhopen, const float* __restrict__ tp0,
                      const float* __restrict__ tp1, const float* __restrict__ wv,
                      const float* __restrict__ Wd, const float* __restrict__ W0,
                      const float* __restrict__ symA, const float* __restrict__ x,
                      const float* __restrict__ cw,
                      float* __restrict__ z2T, float* __restrict__ z1T,
                      float* __restrict__ out) {
    __shared__ float coefs[8*256];
    __shared__ float z2s[8*256];
    __shared__ float sa[64*64];
    __shared__ float xs[8*64];
    __shared__ float cws[64];
    const float* Wd0 = Wd;
    const float* Wd1 = Wd + 65536;
    int n0 = blockIdx.x * 8, t = threadIdx.x;
    float wvt = wv[t];
    #pragma unroll
    for (int j = 0; j < 8; j++) coefs[j*256 + t] = tp1[(n0+j)*256 + t] * wvt;
    #pragma unroll
    for (int i = 0; i < 16; i++) { int f = t + i*256; sa[f] = symA[f]; }
    #pragma unroll
    for (int i = 0; i < 2; i++) { int f = t + i*256; xs[f] = x[n0*64 + f]; }
    if (t < 64) cws[t] = cw[t];
    __syncthreads();
    float acc[8];
    #pragma unroll
    for (int j = 0; j < 8; j++) acc[j] = 0.f;
    for (int m = 0; m < 256; m++) {
        float w = Wd1[m*256 + t];
        #pragma unroll
        for (int j = 0; j < 8; j++) acc[j] += w * coefs[j*256 + m];
    }
    #pragma unroll
    for (int j = 0; j < 8; j++) {
        float v = wvt + 0.5f*acc[j];
        z2s[j*256 + t] = v;
        z2T[(n0+j)*256 + t] = v;
    }
    __syncthreads();
    #pragma unroll
    for (int j = 0; j < 8; j++) coefs[j*256 + t] = tp0[(n0+j)*256 + t] * z2s[j*256 + t];
    __syncthreads();
    #pragma unroll
    for (int j = 0; j < 8; j++) acc[j] = 0.f;
    for (int m = 0; m < 256; m++) {
        float w = Wd0[m*256 + t];
        #pragma unroll
        for (int j = 0; j < 8; j++) acc[j] += w * coefs[j*256 + m];
    }
    #pragma unroll
    for (int j = 0; j < 8; j++) {
        float v = z2s[j*256 + t] + 0.5f*acc[j];
        z2s[j*256 + t] = v;
        z1T[(n0+j)*256 + t] = v;
    }
    __syncthreads();
    #pragma unroll
    for (int j = 0; j < 8; j++) coefs[j*256 + t] = tanhopen[(n0+j)*256 + t] * z2s[j*256 + t];
    __syncthreads();
    int c = t & 63, jj = t >> 6;
    float g[2] = {0.f, 0.f};
    for (int m = 0; m < 256; m++) {
        float w0v = W0[m*64 + c];
        #pragma unroll
        for (int jb = 0; jb < 2; jb++) g[jb] += coefs[(jj + jb*4)*256 + m] * w0v;
    }
    #pragma unroll
    for (int jb = 0; jb < 2; jb++) {
        int j = jj + jb*4;
        float g2 = 0.f;
        for (int jd = 0; jd < 64; jd++) g2 += sa[jd*64 + c] * xs[j*64 + jd];
        out[(n0+j)*64 + c] = g[jb] + g2 + cws[c];
    }
}

// ---------------- heavy per-example Jacobian kernel (bf16-A, hi/lo-B MFMA) ----------------
// One block per example, 512 threads (8 waves), 2 blocks/CU (LDS ~37 KB, VGPR<=128).
// KJ^T = Jac^T @ Wd^T : A = Jac^T (64x256 bf16, swizzled LDS), B = Wd hi/lo (global, L2).
// 16x16x32 MFMA; wave w owns a-tiles {2w, 2w+1}, all 4 d-tiles -> acc[4][2] = 32 VGPRs.
// C layout: col(a)=lane&15, row(d)=(lane>>4)*4+reg.
__global__ __launch_bounds__(512, 4) void k_heavy_mfma(
        const float* __restrict__ tanhopen, const float* __restrict__ tp0,
        const float* __restrict__ tp1, const float* __restrict__ z2T,
        const float* __restrict__ z1T, const float* __restrict__ wv,
        const float* __restrict__ W0T,
        const unsigned short* __restrict__ WdHi, const unsigned short* __restrict__ WdLo,
        const float* __restrict__ ksq, const float* __restrict__ trace,
        float* __restrict__ outTrH) {
    __shared__ __align__(16) unsigned short Jhi[64*256];   // 32 KB
    __shared__ float ss[256], tp0s[256], w1s[256], w2s[256];
    __shared__ float red[8];
    int n = blockIdx.x, t = threadIdx.x;           // t in [0,512)
    int lane = t & 63, w = t >> 6, l15 = lane & 15, lg = lane >> 4;

    float tot = 0.f;
    if (t < 256) {
        float sv   = tanhopen[n*256 + t];
        float tp0v = tp0[n*256 + t];
        float tp1v = tp1[n*256 + t];
        ss[t]   = sv;
        tp0s[t] = tp0v;
        w1s[t]  = (1.f - tp0v*tp0v) * z2T[n*256 + t];
        w2s[t]  = (1.f - tp1v*tp1v) * wv[t];
        tot = (1.f - sv*sv) * z1T[n*256 + t] * ksq[t];   // trH layer-0 partial (m=t)
    }
    __syncthreads();

    // build JacT[d][m] = W0T[d][m]*s[m] (bf16), row 63 zero; vectorized 16B chunks
    #pragma unroll
    for (int i = 0; i < 4; ++i) {
        int q = t + i*512;                 // 2048 chunks
        int d = q >> 5, m0 = (q & 31) << 3;
        short8 v8;
        if (d == 63) {
            #pragma unroll
            for (int e = 0; e < 8; ++e) v8[e] = 0;
        } else {
            const float* wp = &W0T[d*256 + m0];
            #pragma unroll
            for (int e = 0; e < 8; ++e) v8[e] = (short)f2bfu(wp[e] * ss[m0 + e]);
        }
        *reinterpret_cast<short8*>(&Jhi[swz(d, m0)]) = v8;
    }
    __syncthreads();

    floatx4 acc[4][2];

    // ---------------- layer 0: KJ1^T ----------------
    #pragma unroll
    for (int c = 0; c < 4; ++c)
        #pragma unroll
        for (int j = 0; j < 2; ++j)
            acc[c][j] = (floatx4){0.f, 0.f, 0.f, 0.f};

    for (int kk = 0; kk < 8; ++kk) {
        int ko = kk*32 + lg*8;
        short8 Ah[4];
        #pragma unroll
        for (int c = 0; c < 4; ++c)
            Ah[c] = *reinterpret_cast<const short8*>(&Jhi[swz(c*16 + l15, ko)]);
        #pragma unroll
        for (int j = 0; j < 2; ++j) {
            int a = (w*2 + j)*16 + l15;
            short8 Bh = *reinterpret_cast<const short8*>(WdHi + a*256 + ko);
            short8 Bl = *reinterpret_cast<const short8*>(WdLo + a*256 + ko);
            #pragma unroll
            for (int c = 0; c < 4; ++c) {
                acc[c][j] = __builtin_amdgcn_mfma_f32_16x16x32_bf16(Ah[c], Bh, acc[c][j], 0, 0, 0);
                acc[c][j] = __builtin_amdgcn_mfma_f32_16x16x32_bf16(Ah[c], Bl, acc[c][j], 0, 0, 0);
            }
        }
    }
    __syncthreads();   // all layer-0 reads of JacT done before update writes

    // trH layer-1 term + Jac update: JacT[d][a] = W0T[d][a]*s[a] + 0.5*tp0[a]*KJ1T[d][a]
    // (recompute old value in f32 from W0T — no LDS read, single bf16 rounding)
    {
        float w1a[2], tp0a[2], sa[2]; int aidx[2];
        #pragma unroll
        for (int j = 0; j < 2; ++j) {
            int a = (w*2 + j)*16 + l15;
            aidx[j] = a;
            w1a[j]  = w1s[a];
            tp0a[j] = 0.5f * tp0s[a];
            sa[j]   = ss[a];
        }
        #pragma unroll
        for (int c = 0; c < 4; ++c)
            #pragma unroll
            for (int r = 0; r < 4; ++r) {
                int d = c*16 + lg*4 + r;
                #pragma unroll
                for (int j = 0; j < 2; ++j) {
                    float v = acc[c][j][r];
                    tot += 0.5f * w1a[j] * v * v;
                    float base = (d == 63) ? 0.f : W0T[d*256 + aidx[j]] * sa[j];
                    Jhi[swz(d, aidx[j])] = f2bfu(base + tp0a[j] * v);
                }
            }
    }
    __syncthreads();   // updates visible before layer-1 reads

    // ---------------- layer 1: KJ2^T ----------------
    #pragma unroll
    for (int c = 0; c < 4; ++c)
        #pragma unroll
        for (int j = 0; j < 2; ++j)
            acc[c][j] = (floatx4){0.f, 0.f, 0.f, 0.f};

    const unsigned short* W1h = WdHi + 65536;
    const unsigned short* W1l = WdLo + 65536;
    for (int kk = 0; kk < 8; ++kk) {
        int ko = kk*32 + lg*8;
        short8 Ah[4];
        #pragma unroll
        for (int c = 0; c < 4; ++c)
            Ah[c] = *reinterpret_cast<const short8*>(&Jhi[swz(c*16 + l15, ko)]);
        #pragma unroll
        for (int j = 0; j < 2; ++j) {
            int a = (w*2 + j)*16 + l15;
            short8 Bh = *reinterpret_cast<const short8*>(W1h + a*256 + ko);
            short8 Bl = *reinterpret_cast<const short8*>(W1l + a*256 + ko);
            #pragma unroll
            for (int c = 0; c < 4; ++c) {
                acc[c][j] = __builtin_amdgcn_mfma_f32_16x16x32_bf16(Ah[c], Bh, acc[c][j], 0, 0, 0);
                acc[c][j] = __builtin_amdgcn_mfma_f32_16x16x32_bf16(Ah[c], Bl, acc[c][j], 0, 0, 0);
            }
        }
    }

    // trH layer-2 term
    {
        float w2a[2];
        #pragma unroll
        for (int j = 0; j < 2; ++j) w2a[j] = w2s[(w*2 + j)*16 + l15];
        #pragma unroll
        for (int c = 0; c < 4; ++c)
            #pragma unroll
            for (int j = 0; j < 2; ++j)
                #pragma unroll
                for (int r = 0; r < 4; ++r) {
                    float v = acc[c][j][r];
                    tot += 0.5f * w2a[j] * v * v;
                }
    }

    // reduce 512 -> 1
    for (int off = 32; off; off >>= 1) tot += __shfl_down(tot, off, 64);
    if (lane == 0) red[w] = tot;
    __syncthreads();
    if (t == 0) {
        float s = trace[0];
        #pragma unroll
        for (int i = 0; i < 8; ++i) s += red[i];
        outTrH[n] = s;
    }
}

// ---------------- launcher ----------------

extern "C" void kernel_launch(void* const* d_in, const int* in_sizes, int n_in,
                              void* d_out, int out_size, void* d_ws, size_t ws_size,
                              hipStream_t stream) {
    const float* x   = (const float*)d_in[0];   // 4096*64
    const float* W0  = (const float*)d_in[1];   // 256*64
    const float* b0  = (const float*)d_in[2];   // 256
    const float* Wd  = (const float*)d_in[3];   // 2*256*256
    const float* bd  = (const float*)d_in[4];   // 2*256
    const float* wv  = (const float*)d_in[5];   // 256
    const float* A   = (const float*)d_in[6];   // 10*64
    const float* cw  = (const float*)d_in[7];   // 64
    float* out = (float*)d_out;
    float* ws  = (float*)d_ws;

    float* tanhopen = ws;               // NM
    float* tp0  = tanhopen + NM;        // NM
    float* tp1  = tp0 + NM;             // NM
    float* z2T  = tp1 + NM;             // NM
    float* z1T  = z2T + NM;             // NM
    float* Wd0T = z1T + NM;             // 65536
    float* Wd1T = Wd0T + 65536;         // 65536
    float* W0T  = Wd1T + 65536;         // 16384
    float* symA = W0T + 16384;          // 4096
    float* ksq  = symA + 4096;          // 256
    float* trace= ksq + 256;            // 1
    unsigned short* WdHi = (unsigned short*)(trace + 1);  // 131072 ushorts
    unsigned short* WdLo = WdHi + 131072;                 // 131072 ushorts

    k_prep<<<1105, 256, 0, stream>>>(Wd, W0, A, WdHi, WdLo, Wd0T, Wd1T, W0T,
                                     symA, ksq, trace);
    k_fwd<<<NEX/8, 256, 0, stream>>>(x, W0T, b0, Wd0T, Wd1T, bd,
                                     tanhopen, tp0, tp1);
    k_bwd<<<NEX/8, 256, 0, stream>>>(tanhopen, tp0, tp1, wv, Wd, W0, symA, x, cw,
                                     z2T, z1T, out);
    k_heavy_mfma<<<NEX, 512, 0, stream>>>(tanhopen, tp0, tp1, z2T, z1T, wv,
                                          W0T, WdHi, WdLo, ksq, trace, out + NEX*64);
}

// Round 5
// 343.020 us; speedup vs baseline: 4.9218x; 1.0032x over previous
//
#include <hip/hip_runtime.h>
#include <hip/hip_bf16.h>

#define NEX 4096
#define M   256
#define NM  (NEX*M)

typedef __attribute__((ext_vector_type(8))) short short8;
typedef __attribute__((ext_vector_type(4))) float floatx4;

__device__ inline unsigned short f2bfu(float x) {
    __hip_bfloat16 h = __float2bfloat16(x);
    union { __hip_bfloat16 b; unsigned short u; } cv; cv.b = h;
    return cv.u;
}
__device__ inline float bfu2f(unsigned short u) {
    union { unsigned short u; __hip_bfloat16 b; } cv; cv.u = u;
    return __bfloat162float(cv.b);
}

// swizzled element offset for [64][256] bf16 LDS tile, 16B-chunk XOR
__device__ inline int swz(int row, int col) {
    return row*256 + ((((col >> 3) ^ (row & 7)) << 3) | (col & 7));
}

// ---------------- fused prep kernel ----------------
__global__ void k_prep(const float* __restrict__ Wd, const float* __restrict__ W0,
                       const float* __restrict__ A,
                       unsigned short* __restrict__ WdHi, unsigned short* __restrict__ WdLo,
                       float* __restrict__ Wd0T, float* __restrict__ Wd1T,
                       float* __restrict__ W0T, float* __restrict__ symA,
                       float* __restrict__ ksq, float* __restrict__ trace) {
    int b = blockIdx.x, t = threadIdx.x;
    if (b < 512) {
        int idx = b*256 + t;
        float x = Wd[idx];
        unsigned short h = f2bfu(x);
        WdHi[idx] = h;
        WdLo[idx] = f2bfu(x - bfu2f(h));
    } else if (b < 768) {
        int idx = (b-512)*256 + t;          // dst index c*256+r
        int c = idx >> 8, r = idx & 255;
        Wd0T[idx] = Wd[r*256 + c];
    } else if (b < 1024) {
        int idx = (b-768)*256 + t;
        int c = idx >> 8, r = idx & 255;
        Wd1T[idx] = Wd[65536 + r*256 + c];
    } else if (b < 1088) {
        int idx = (b-1024)*256 + t;         // 16384 entries: c*256+r, c<64
        int c = idx >> 8, r = idx & 255;
        W0T[idx] = W0[r*64 + c];
    } else if (b == 1088) {
        float s = 0.f;
        for (int dd = 0; dd < 63; dd++) { float v = W0[t*64+dd]; s += v*v; }
        ksq[t] = s;
        float p = 0.f;
        for (int idx = t; idx < 630; idx += 256) {
            int r = idx / 63, i = idx % 63;
            float v = A[r*64+i]; p += v*v;
        }
        for (int off = 32; off; off >>= 1) p += __shfl_down(p, off, 64);
        __shared__ float red[4];
        if ((t & 63) == 0) red[t >> 6] = p;
        __syncthreads();
        if (t == 0) trace[0] = red[0]+red[1]+red[2]+red[3];
    } else {
        int idx = (b-1089)*256 + t;         // 4096 entries
        int i = idx >> 6, j = idx & 63;
        float s = 0.f;
        #pragma unroll
        for (int r = 0; r < 10; r++) s += A[r*64+i] * A[r*64+j];
        symA[idx] = s;
    }
}

// ---------------- fused forward chain: opening + pre0 + pre1 ----------------
__global__ void k_fwd(const float* __restrict__ x, const float* __restrict__ W0T,
                      const float* __restrict__ b0, const float* __restrict__ Wd0T,
                      const float* __restrict__ Wd1T, const float* __restrict__ bd,
                      float* __restrict__ tanhopen, float* __restrict__ tp0,
                      float* __restrict__ tp1) {
    __shared__ float xs[8*64];
    __shared__ float u0s[8*256];
    __shared__ float u1s[8*256];
    int n0 = blockIdx.x * 8, t = threadIdx.x;
    #pragma unroll
    for (int i = 0; i < 2; i++) { int f = t + i*256; xs[f] = x[n0*64 + f]; }
    __syncthreads();
    float acc[8];
    float b = b0[t];
    #pragma unroll
    for (int j = 0; j < 8; j++) acc[j] = b;
    for (int c = 0; c < 64; c++) {
        float w = W0T[c*256 + t];
        #pragma unroll
        for (int j = 0; j < 8; j++) acc[j] += w * xs[j*64 + c];
    }
    #pragma unroll
    for (int j = 0; j < 8; j++) {
        float p = acc[j];
        tanhopen[(n0+j)*256 + t] = tanhf(p);
        float a = fabsf(p);
        u0s[j*256 + t] = a + log1pf(expf(-2.f*a));
    }
    __syncthreads();
    b = bd[t];
    #pragma unroll
    for (int j = 0; j < 8; j++) acc[j] = b;
    for (int k = 0; k < 256; k++) {
        float w = Wd0T[k*256 + t];
        #pragma unroll
        for (int j = 0; j < 8; j++) acc[j] += w * u0s[j*256 + k];
    }
    #pragma unroll
    for (int j = 0; j < 8; j++) {
        float p = acc[j];
        tp0[(n0+j)*256 + t] = tanhf(p);
        float a = fabsf(p);
        u1s[j*256 + t] = u0s[j*256 + t] + 0.5f*(a + log1pf(expf(-2.f*a)));
    }
    __syncthreads();
    b = bd[256 + t];
    #pragma unroll
    for (int j = 0; j < 8; j++) acc[j] = b;
    for (int k = 0; k < 256; k++) {
        float w = Wd1T[k*256 + t];
        #pragma unroll
        for (int j = 0; j < 8; j++) acc[j] += w * u1s[j*256 + k];
    }
    #pragma unroll
    for (int j = 0; j < 8; j++) tp1[(n0+j)*256 + t] = tanhf(acc[j]);
}

// ---------------- fused backward chain: z2 + z1 + grad ----------------
__global__ void k_bwd(const float* __restrict__ tanhopen, const float* __restrict__ tp0,
                      const float* __restrict__ tp1, const float* __restrict__ wv,
                      const float* __restrict__ Wd, const float* __restrict__ W0,
                      const float* __restrict__ symA, const float* __restrict__ x,
                      const float* __restrict__ cw,
                      float* __restrict__ z2T, float* __restrict__ z1T,
                      float* __restrict__ out) {
    __shared__ float coefs[8*256];
    __shared__ float z2s[8*256];
    __shared__ float sa[64*64];
    __shared__ float xs[8*64];
    __shared__ float cws[64];
    const float* Wd0 = Wd;
    const float* Wd1 = Wd + 65536;
    int n0 = blockIdx.x * 8, t = threadIdx.x;
    float wvt = wv[t];
    #pragma unroll
    for (int j = 0; j < 8; j++) coefs[j*256 + t] = tp1[(n0+j)*256 + t] * wvt;
    #pragma unroll
    for (int i = 0; i < 16; i++) { int f = t + i*256; sa[f] = symA[f]; }
    #pragma unroll
    for (int i = 0; i < 2; i++) { int f = t + i*256; xs[f] = x[n0*64 + f]; }
    if (t < 64) cws[t] = cw[t];
    __syncthreads();
    float acc[8];
    #pragma unroll
    for (int j = 0; j < 8; j++) acc[j] = 0.f;
    for (int m = 0; m < 256; m++) {
        float w = Wd1[m*256 + t];
        #pragma unroll
        for (int j = 0; j < 8; j++) acc[j] += w * coefs[j*256 + m];
    }
    #pragma unroll
    for (int j = 0; j < 8; j++) {
        float v = wvt + 0.5f*acc[j];
        z2s[j*256 + t] = v;
        z2T[(n0+j)*256 + t] = v;
    }
    __syncthreads();
    #pragma unroll
    for (int j = 0; j < 8; j++) coefs[j*256 + t] = tp0[(n0+j)*256 + t] * z2s[j*256 + t];
    __syncthreads();
    #pragma unroll
    for (int j = 0; j < 8; j++) acc[j] = 0.f;
    for (int m = 0; m < 256; m++) {
        float w = Wd0[m*256 + t];
        #pragma unroll
        for (int j = 0; j < 8; j++) acc[j] += w * coefs[j*256 + m];
    }
    #pragma unroll
    for (int j = 0; j < 8; j++) {
        float v = z2s[j*256 + t] + 0.5f*acc[j];
        z2s[j*256 + t] = v;
        z1T[(n0+j)*256 + t] = v;
    }
    __syncthreads();
    #pragma unroll
    for (int j = 0; j < 8; j++) coefs[j*256 + t] = tanhopen[(n0+j)*256 + t] * z2s[j*256 + t];
    __syncthreads();
    int c = t & 63, jj = t >> 6;
    float g[2] = {0.f, 0.f};
    for (int m = 0; m < 256; m++) {
        float w0v = W0[m*64 + c];
        #pragma unroll
        for (int jb = 0; jb < 2; jb++) g[jb] += coefs[(jj + jb*4)*256 + m] * w0v;
    }
    #pragma unroll
    for (int jb = 0; jb < 2; jb++) {
        int j = jj + jb*4;
        float g2 = 0.f;
        for (int jd = 0; jd < 64; jd++) g2 += sa[jd*64 + c] * xs[j*64 + jd];
        out[(n0+j)*64 + c] = g[jb] + g2 + cws[c];
    }
}

// ---------------- heavy per-example Jacobian kernel (bf16-A, hi/lo-B MFMA) ----------------
// One block per example, 256 threads (4 waves), target 4 blocks/CU (LDS ~36 KB, VGPR ~124).
// KJ^T = Jac^T @ Wd^T : A = Jac^T (64x256 bf16, swizzled LDS), B = Wd hi/lo (global, L2).
// 16x16x32 MFMA; wave w owns a-tiles 4w..4w+3 (j=4: each A-read feeds 32 MFMA),
// all 4 d-tiles -> acc[4][4] = 64 VGPRs.
// C layout: col(a)=lane&15, row(d)=(lane>>4)*4+reg.
__global__ __launch_bounds__(256, 2) void k_heavy_mfma(
        const float* __restrict__ tanhopen, const float* __restrict__ tp0,
        const float* __restrict__ tp1, const float* __restrict__ z2T,
        const float* __restrict__ z1T, const float* __restrict__ wv,
        const float* __restrict__ W0T,
        const unsigned short* __restrict__ WdHi, const unsigned short* __restrict__ WdLo,
        const float* __restrict__ ksq, const float* __restrict__ trace,
        float* __restrict__ outTrH) {
    __shared__ __align__(16) unsigned short Jhi[64*256];   // 32 KB
    __shared__ float ss[256], tp0s[256], w1s[256], w2s[256];
    __shared__ float red[4];
    int n = blockIdx.x, t = threadIdx.x;           // t in [0,256)
    int lane = t & 63, w = t >> 6, l15 = lane & 15, lg = lane >> 4;

    float sv   = tanhopen[n*256 + t];
    float tp0v = tp0[n*256 + t];
    float tp1v = tp1[n*256 + t];
    ss[t]   = sv;
    tp0s[t] = tp0v;
    w1s[t]  = (1.f - tp0v*tp0v) * z2T[n*256 + t];
    w2s[t]  = (1.f - tp1v*tp1v) * wv[t];
    float tot = (1.f - sv*sv) * z1T[n*256 + t] * ksq[t];   // trH layer-0 partial (m=t)
    __syncthreads();

    // build JacT[d][m] = W0T[d][m]*s[m] (bf16), row 63 zero; vectorized 16B chunks
    #pragma unroll
    for (int i = 0; i < 8; ++i) {
        int q = t + i*256;                 // 2048 chunks
        int d = q >> 5, m0 = (q & 31) << 3;
        short8 v8;
        if (d == 63) {
            #pragma unroll
            for (int e = 0; e < 8; ++e) v8[e] = 0;
        } else {
            const float* wp = &W0T[d*256 + m0];
            #pragma unroll
            for (int e = 0; e < 8; ++e) v8[e] = (short)f2bfu(wp[e] * ss[m0 + e]);
        }
        *reinterpret_cast<short8*>(&Jhi[swz(d, m0)]) = v8;
    }
    __syncthreads();

    floatx4 acc[4][4];   // [d-tile c][a-tile j]

    // ---------------- layer 0: KJ1^T ----------------
    #pragma unroll
    for (int c = 0; c < 4; ++c)
        #pragma unroll
        for (int j = 0; j < 4; ++j)
            acc[c][j] = (floatx4){0.f, 0.f, 0.f, 0.f};

    for (int kk = 0; kk < 8; ++kk) {
        int ko = kk*32 + lg*8;
        short8 Ah[4];
        #pragma unroll
        for (int c = 0; c < 4; ++c)
            Ah[c] = *reinterpret_cast<const short8*>(&Jhi[swz(c*16 + l15, ko)]);
        #pragma unroll
        for (int j = 0; j < 4; ++j) {
            int a = (w*4 + j)*16 + l15;
            short8 Bh = *reinterpret_cast<const short8*>(WdHi + a*256 + ko);
            short8 Bl = *reinterpret_cast<const short8*>(WdLo + a*256 + ko);
            #pragma unroll
            for (int c = 0; c < 4; ++c) {
                acc[c][j] = __builtin_amdgcn_mfma_f32_16x16x32_bf16(Ah[c], Bh, acc[c][j], 0, 0, 0);
                acc[c][j] = __builtin_amdgcn_mfma_f32_16x16x32_bf16(Ah[c], Bl, acc[c][j], 0, 0, 0);
            }
        }
    }
    __syncthreads();   // all layer-0 reads of JacT done before update writes

    // trH layer-1 term + Jac update (LDS RMW): JacT[d][a] += 0.5*tp0[a]*KJ1T[d][a]
    {
        float w1a[4], tp0a[4]; int aidx[4];
        #pragma unroll
        for (int j = 0; j < 4; ++j) {
            int a = (w*4 + j)*16 + l15;
            aidx[j] = a;
            w1a[j]  = w1s[a];
            tp0a[j] = 0.5f * tp0s[a];
        }
        #pragma unroll
        for (int c = 0; c < 4; ++c)
            #pragma unroll
            for (int r = 0; r < 4; ++r) {
                int d = c*16 + lg*4 + r;
                #pragma unroll
                for (int j = 0; j < 4; ++j) {
                    float v = acc[c][j][r];
                    tot += 0.5f * w1a[j] * v * v;
                    int off = swz(d, aidx[j]);
                    Jhi[off] = f2bfu(bfu2f(Jhi[off]) + tp0a[j] * v);
                }
            }
    }
    __syncthreads();   // updates visible before layer-1 reads

    // ---------------- layer 1: KJ2^T ----------------
    #pragma unroll
    for (int c = 0; c < 4; ++c)
        #pragma unroll
        for (int j = 0; j < 4; ++j)
            acc[c][j] = (floatx4){0.f, 0.f, 0.f, 0.f};

    const unsigned short* W1h = WdHi + 65536;
    const unsigned short* W1l = WdLo + 65536;
    for (int kk = 0; kk < 8; ++kk) {
        int ko = kk*32 + lg*8;
        short8 Ah[4];
        #pragma unroll
        for (int c = 0; c < 4; ++c)
            Ah[c] = *reinterpret_cast<const short8*>(&Jhi[swz(c*16 + l15, ko)]);
        #pragma unroll
        for (int j = 0; j < 4; ++j) {
            int a = (w*4 + j)*16 + l15;
            short8 Bh = *reinterpret_cast<const short8*>(W1h + a*256 + ko);
            short8 Bl = *reinterpret_cast<const short8*>(W1l + a*256 + ko);
            #pragma unroll
            for (int c = 0; c < 4; ++c) {
                acc[c][j] = __builtin_amdgcn_mfma_f32_16x16x32_bf16(Ah[c], Bh, acc[c][j], 0, 0, 0);
                acc[c][j] = __builtin_amdgcn_mfma_f32_16x16x32_bf16(Ah[c], Bl, acc[c][j], 0, 0, 0);
            }
        }
    }

    // trH layer-2 term
    {
        float w2a[4];
        #pragma unroll
        for (int j = 0; j < 4; ++j) w2a[j] = w2s[(w*4 + j)*16 + l15];
        #pragma unroll
        for (int c = 0; c < 4; ++c)
            #pragma unroll
            for (int j = 0; j < 4; ++j)
                #pragma unroll
                for (int r = 0; r < 4; ++r) {
                    float v = acc[c][j][r];
                    tot += 0.5f * w2a[j] * v * v;
                }
    }

    // reduce 256 -> 1
    for (int off = 32; off; off >>= 1) tot += __shfl_down(tot, off, 64);
    if (lane == 0) red[w] = tot;
    __syncthreads();
    if (t == 0) outTrH[n] = red[0] + red[1] + red[2] + red[3] + trace[0];
}

// ---------------- launcher ----------------

extern "C" void kernel_launch(void* const* d_in, const int* in_sizes, int n_in,
                              void* d_out, int out_size, void* d_ws, size_t ws_size,
                              hipStream_t stream) {
    const float* x   = (const float*)d_in[0];   // 4096*64
    const float* W0  = (const float*)d_in[1];   // 256*64
    const float* b0  = (const float*)d_in[2];   // 256
    const float* Wd  = (const float*)d_in[3];   // 2*256*256
    const float* bd  = (const float*)d_in[4];   // 2*256
    const float* wv  = (const float*)d_in[5];   // 256
    const float* A   = (const float*)d_in[6];   // 10*64
    const float* cw  = (const float*)d_in[7];   // 64
    float* out = (float*)d_out;
    float* ws  = (float*)d_ws;

    float* tanhopen = ws;               // NM
    float* tp0  = tanhopen + NM;        // NM
    float* tp1  = tp0 + NM;             // NM
    float* z2T  = tp1 + NM;             // NM
    float* z1T  = z2T + NM;             // NM
    float* Wd0T = z1T + NM;             // 65536
    float* Wd1T = Wd0T + 65536;         // 65536
    float* W0T  = Wd1T + 65536;         // 16384
    float* symA = W0T + 16384;          // 4096
    float* ksq  = symA + 4096;          // 256
    float* trace= ksq + 256;            // 1
    unsigned short* WdHi = (unsigned short*)(trace + 1);  // 131072 ushorts
    unsigned short* WdLo = WdHi + 131072;                 // 131072 ushorts

    k_prep<<<1105, 256, 0, stream>>>(Wd, W0, A, WdHi, WdLo, Wd0T, Wd1T, W0T,
                                     symA, ksq, trace);
    k_fwd<<<NEX/8, 256, 0, stream>>>(x, W0T, b0, Wd0T, Wd1T, bd,
                                     tanhopen, tp0, tp1);
    k_bwd<<<NEX/8, 256, 0, stream>>>(tanhopen, tp0, tp1, wv, Wd, W0, symA, x, cw,
                                     z2T, z1T, out);
    k_heavy_mfma<<<NEX, 256, 0, stream>>>(tanhopen, tp0, tp1, z2T, z1T, wv,
                                          W0T, WdHi, WdLo, ksq, trace, out + NEX*64);
}